// Round 1
// baseline (1826.134 us; speedup 1.0000x reference)
//
#include <hip/hip_runtime.h>
#include <hip/hip_bf16.h>
#include <cstdint>
#include <cstddef>

typedef __bf16 bf16_t;
typedef __bf16 bf16x4_v __attribute__((ext_vector_type(4)));
typedef __bf16 bf16x8_v __attribute__((ext_vector_type(8)));
typedef float  f32x4_v  __attribute__((ext_vector_type(4)));

#define BM 128
#define BN 128
#define BK 64

// async global->LDS, 16B per lane. LDS dest must be wave-uniform base; HW adds lane*16.
__device__ __forceinline__ void gll16(const void* g, void* l) {
  __builtin_amdgcn_global_load_lds(
      (const __attribute__((address_space(1))) void*)g,
      (__attribute__((address_space(3))) void*)l,
      16, 0, 0);
}

__device__ __forceinline__ float gelu_tanh(float x) {
  float x3 = x * x * x;
  float t = tanhf(0.79788456080286535588f * (x + 0.044715f * x3));
  return 0.5f * x * (1.0f + t);
}

// ---------------------------------------------------------------- LayerNorm
// one row of 1024 per block (256 threads, 4 floats/thread), write bf16
__global__ __launch_bounds__(256) void ln_kernel(
    const float* __restrict__ X, const float* __restrict__ sc,
    const float* __restrict__ off, bf16_t* __restrict__ Y)
{
  const int row = blockIdx.x;
  const int tid = threadIdx.x;
  const float4 v = *(const float4*)&X[(size_t)row * 1024 + tid * 4];
  float s  = v.x + v.y + v.z + v.w;
  float s2 = v.x * v.x + v.y * v.y + v.z * v.z + v.w * v.w;
#pragma unroll
  for (int m = 1; m < 64; m <<= 1) {
    s  += __shfl_xor(s, m);
    s2 += __shfl_xor(s2, m);
  }
  __shared__ float red[8];
  const int wid = tid >> 6;
  if ((tid & 63) == 0) { red[wid] = s; red[4 + wid] = s2; }
  __syncthreads();
  s  = red[0] + red[1] + red[2] + red[3];
  s2 = red[4] + red[5] + red[6] + red[7];
  const float mu  = s * (1.0f / 1024.0f);
  float var = s2 * (1.0f / 1024.0f) - mu * mu;
  var = fmaxf(var, 0.0f);
  const float rs = rsqrtf(var + 1e-5f);
  const float4 g = *(const float4*)&sc[tid * 4];
  const float4 o = *(const float4*)&off[tid * 4];
  bf16x4_v y;
  y[0] = (bf16_t)((v.x - mu) * rs * g.x + o.x);
  y[1] = (bf16_t)((v.y - mu) * rs * g.y + o.y);
  y[2] = (bf16_t)((v.z - mu) * rs * g.z + o.z);
  y[3] = (bf16_t)((v.w - mu) * rs * g.w + o.w);
  *(bf16x4_v*)&Y[(size_t)row * 1024 + tid * 4] = y;
}

// ------------------------------------------------------- transpose f32->bf16
// Wt[c][r] = Win[r][c];  R,C multiples of 32. grid = (C/32, R/32), 256 thr.
__global__ __launch_bounds__(256) void transpose_kernel(
    const float* __restrict__ Win, bf16_t* __restrict__ Wt, int R, int C)
{
  __shared__ float t[32][33];
  const int tx = threadIdx.x & 31;
  const int ty = (threadIdx.x >> 5) << 2;  // 0,4,..,28
  const int r0 = blockIdx.y * 32;
  const int c0 = blockIdx.x * 32;
#pragma unroll
  for (int r = 0; r < 4; ++r)
    t[ty + r][tx] = Win[(size_t)(r0 + ty + r) * C + (c0 + tx)];
  __syncthreads();
#pragma unroll
  for (int r = 0; r < 4; ++r)
    Wt[(size_t)(c0 + ty + r) * R + (r0 + tx)] = (bf16_t)t[tx][ty + r];
}

// ---------------------------------------------------------------- GEMM 1
// H[b_local*4+k][m] = gelu( sum_f Y[b][f] * W1t[m][(f - k*1024) mod 4096] + b1[m] )
// grid = (cb/128, 128);  blockIdx.y -> (kgrp = y>>5, m-tile = y&31)
__global__ __launch_bounds__(256) void gemm1_kernel(
    const bf16_t* __restrict__ Y, const bf16_t* __restrict__ W1t,
    const float* __restrict__ b1, bf16_t* __restrict__ H, int b0_base)
{
  __shared__ __align__(16) bf16_t As[BM * BK];
  __shared__ __align__(16) bf16_t Bs[BN * BK];

  const int tid  = threadIdx.x;
  const int lane = tid & 63;
  const int wid  = tid >> 6;
  const int wm   = wid >> 1;
  const int wn   = wid & 1;

  const int bm   = blockIdx.x;
  const int bn   = blockIdx.y;
  const int kgrp = bn >> 5;
  const int m0   = (bn & 31) * BN;
  const long b0  = (long)b0_base + (long)bm * BM;

  const int arow = tid >> 3;          // +32 per staging round
  const int acol = (tid & 7) << 3;

  f32x4_v acc[4][4] = {};

  const bf16_t* Abase = Y   + (size_t)(b0 + arow) * 4096 + acol;
  const bf16_t* Bbase = W1t + (size_t)(m0 + arow) * 4096 + acol;
  char* AsB = (char*)As;
  char* BsB = (char*)Bs;
  const int ldsw = wid * 1024;

  for (int kt = 0; kt < 4096 / BK; ++kt) {
    const int f0  = kt * BK;
    const int cB0 = (f0 + (4 - kgrp) * 1024) & 4095;   // rolled column base
    const bf16_t* Ag = Abase + f0;
    const bf16_t* Bg = Bbase + cB0;
#pragma unroll
    for (int rd = 0; rd < 4; ++rd)
      gll16(Ag + (size_t)rd * 32 * 4096, AsB + rd * 4096 + ldsw);
#pragma unroll
    for (int rd = 0; rd < 4; ++rd)
      gll16(Bg + (size_t)rd * 32 * 4096, BsB + rd * 4096 + ldsw);
    __syncthreads();

#pragma unroll
    for (int s = 0; s < 2; ++s) {
      const int kc = s * 32 + (lane >> 4) * 8;
      const int rA = lane & 15;
      bf16x8_v a[4], b[4];
#pragma unroll
      for (int i = 0; i < 4; ++i)
        a[i] = *(const bf16x8_v*)&As[(wm * 64 + i * 16 + rA) * BK + kc];
#pragma unroll
      for (int j = 0; j < 4; ++j)
        b[j] = *(const bf16x8_v*)&Bs[(wn * 64 + j * 16 + rA) * BK + kc];
#pragma unroll
      for (int i = 0; i < 4; ++i)
#pragma unroll
        for (int j = 0; j < 4; ++j)
          acc[i][j] = __builtin_amdgcn_mfma_f32_16x16x32_bf16(a[i], b[j], acc[i][j], 0, 0, 0);
    }
    __syncthreads();
  }

  // epilogue: +b1, gelu, store bf16 into H[(b_local*4 + kgrp)][m]
  const int rbase = (lane >> 4) * 4;
  const int cbase = lane & 15;
#pragma unroll
  for (int i = 0; i < 4; ++i) {
    const long brow_l = (long)bm * BM + wm * 64 + i * 16 + rbase;  // chunk-local batch row
#pragma unroll
    for (int j = 0; j < 4; ++j) {
      const int m = m0 + wn * 64 + j * 16 + cbase;
      const float bias = b1[m];
#pragma unroll
      for (int r = 0; r < 4; ++r) {
        float v = acc[i][j][r] + bias;
        v = gelu_tanh(v);
        H[((size_t)(brow_l + r) * 4 + kgrp) * 4096 + m] = (bf16_t)v;
      }
    }
  }
}

// ---------------------------------------------------------------- GEMM 2
// OUT[rg][w] = X[rg][w] + sum_m H[rl][m] * W2t[w][m] + b2[w]
// grid = (cb*4/128, 8)
__global__ __launch_bounds__(256) void gemm2_kernel(
    const bf16_t* __restrict__ H, const bf16_t* __restrict__ W2t,
    const float* __restrict__ b2, const float* __restrict__ X,
    float* __restrict__ OUT, long r0_base)
{
  __shared__ __align__(16) bf16_t As[BM * BK];
  __shared__ __align__(16) bf16_t Bs[BN * BK];

  const int tid  = threadIdx.x;
  const int lane = tid & 63;
  const int wid  = tid >> 6;
  const int wm   = wid >> 1;
  const int wn   = wid & 1;

  const int bm = blockIdx.x;
  const int n0 = blockIdx.y * BN;

  const int arow = tid >> 3;
  const int acol = (tid & 7) << 3;

  f32x4_v acc[4][4] = {};

  const bf16_t* Abase = H   + (size_t)(bm * BM + arow) * 4096 + acol;
  const bf16_t* Bbase = W2t + (size_t)(n0 + arow) * 4096 + acol;
  char* AsB = (char*)As;
  char* BsB = (char*)Bs;
  const int ldsw = wid * 1024;

  for (int kt = 0; kt < 4096 / BK; ++kt) {
    const int f0 = kt * BK;
    const bf16_t* Ag = Abase + f0;
    const bf16_t* Bg = Bbase + f0;
#pragma unroll
    for (int rd = 0; rd < 4; ++rd)
      gll16(Ag + (size_t)rd * 32 * 4096, AsB + rd * 4096 + ldsw);
#pragma unroll
    for (int rd = 0; rd < 4; ++rd)
      gll16(Bg + (size_t)rd * 32 * 4096, BsB + rd * 4096 + ldsw);
    __syncthreads();

#pragma unroll
    for (int s = 0; s < 2; ++s) {
      const int kc = s * 32 + (lane >> 4) * 8;
      const int rA = lane & 15;
      bf16x8_v a[4], b[4];
#pragma unroll
      for (int i = 0; i < 4; ++i)
        a[i] = *(const bf16x8_v*)&As[(wm * 64 + i * 16 + rA) * BK + kc];
#pragma unroll
      for (int j = 0; j < 4; ++j)
        b[j] = *(const bf16x8_v*)&Bs[(wn * 64 + j * 16 + rA) * BK + kc];
#pragma unroll
      for (int i = 0; i < 4; ++i)
#pragma unroll
        for (int j = 0; j < 4; ++j)
          acc[i][j] = __builtin_amdgcn_mfma_f32_16x16x32_bf16(a[i], b[j], acc[i][j], 0, 0, 0);
    }
    __syncthreads();
  }

  const int rbase = (lane >> 4) * 4;
  const int cbase = lane & 15;
#pragma unroll
  for (int i = 0; i < 4; ++i) {
    const long rl = (long)bm * BM + wm * 64 + i * 16 + rbase;  // chunk-local row
#pragma unroll
    for (int j = 0; j < 4; ++j) {
      const int w = n0 + wn * 64 + j * 16 + cbase;
      const float bias = b2[w];
#pragma unroll
      for (int r = 0; r < 4; ++r) {
        const size_t rg = (size_t)(r0_base + rl + r);
        OUT[rg * 1024 + w] = X[rg * 1024 + w] + acc[i][j][r] + bias;
      }
    }
  }
}

// ----------------------------------------------------------------- launch
extern "C" void kernel_launch(void* const* d_in, const int* in_sizes, int n_in,
                              void* d_out, int out_size, void* d_ws, size_t ws_size,
                              hipStream_t stream)
{
  const float* x   = (const float*)d_in[0];
  const float* lns = (const float*)d_in[1];
  const float* lno = (const float*)d_in[2];
  const float* W1  = (const float*)d_in[3];
  const float* b1  = (const float*)d_in[4];
  const float* W2  = (const float*)d_in[5];
  const float* b2  = (const float*)d_in[6];
  float* out = (float*)d_out;

  char* ws = (char*)d_ws;
  const size_t W1OFF = (size_t)64 << 20;   // Y: 64 MB
  const size_t W2OFF = (size_t)96 << 20;   // W1t: 32 MB
  const size_t HOFF  = (size_t)104 << 20;  // W2t: 8 MB
  bf16_t* Y   = (bf16_t*)(ws);
  bf16_t* W1t = (bf16_t*)(ws + W1OFF);
  bf16_t* W2t = (bf16_t*)(ws + W2OFF);
  bf16_t* H   = (bf16_t*)(ws + HOFF);

  ln_kernel<<<32768, 256, 0, stream>>>(x, lns, lno, Y);
  transpose_kernel<<<dim3(128, 128), 256, 0, stream>>>(W1, W1t, 4096, 4096);
  transpose_kernel<<<dim3(32, 128), 256, 0, stream>>>(W2, W2t, 4096, 1024);

  // batch-chunked to fit H (4*4096*2 = 32 KB per batch row) in remaining ws
  const size_t per_row = (size_t)4 * 4096 * 2;
  long chunk = 8192;
  if (ws_size < HOFF + (size_t)8192 * per_row) {
    long maxb = (long)((ws_size - HOFF) / per_row);
    chunk = maxb & ~127L;
    if (chunk < 128) chunk = 128;
  }
  for (long b0 = 0; b0 < 8192; b0 += chunk) {
    const long cb = (8192 - b0 < chunk) ? (8192 - b0) : chunk;
    gemm1_kernel<<<dim3(cb / 128, 128), 256, 0, stream>>>(Y, W1t, b1, H, (int)b0);
    gemm2_kernel<<<dim3((cb * 4) / 128, 8), 256, 0, stream>>>(H, W2t, b2, x, out, b0 * 4);
  }
}

// Round 3
// 1512.993 us; speedup vs baseline: 1.2070x; 1.2070x over previous
//
#include <hip/hip_runtime.h>
#include <hip/hip_bf16.h>
#include <cstdint>
#include <cstddef>

typedef __bf16 bf16_t;
typedef __bf16 bf16x4_v __attribute__((ext_vector_type(4)));
typedef __bf16 bf16x8_v __attribute__((ext_vector_type(8)));
typedef float  f32x4_v  __attribute__((ext_vector_type(4)));

// async global->LDS, 16B/lane; LDS dest = wave-uniform base + lane*16
__device__ __forceinline__ void gll16(const void* g, void* l) {
  __builtin_amdgcn_global_load_lds(
      (const __attribute__((address_space(1))) void*)g,
      (__attribute__((address_space(3))) void*)l, 16, 0, 0);
}

// raw barrier: does NOT drain vmcnt (unlike __syncthreads); "memory" clobber
// pins LDS reads / gll issues on their side of it.
#define BARRIER()  asm volatile("s_barrier" ::: "memory")
#define WAIT_VM0() asm volatile("s_waitcnt vmcnt(0)" ::: "memory")

__device__ __forceinline__ float gelu_tanh(float x) {
  // 0.5x(1+tanh(z)) == x * sigmoid(2z); NaN-free at extremes
  float z = 0.79788456080286535588f * (x + 0.044715f * x * x * x);
  return x / (1.0f + __expf(-2.0f * z));
}

// ---------------------------------------------------------------- LayerNorm
__global__ __launch_bounds__(256) void ln_kernel(
    const float* __restrict__ X, const float* __restrict__ sc,
    const float* __restrict__ off, bf16_t* __restrict__ Y)
{
  const int row = blockIdx.x;
  const int tid = threadIdx.x;
  const float4 v = *(const float4*)&X[(size_t)row * 1024 + tid * 4];
  float s  = v.x + v.y + v.z + v.w;
  float s2 = v.x * v.x + v.y * v.y + v.z * v.z + v.w * v.w;
#pragma unroll
  for (int m = 1; m < 64; m <<= 1) {
    s  += __shfl_xor(s, m);
    s2 += __shfl_xor(s2, m);
  }
  __shared__ float red[8];
  const int wid = tid >> 6;
  if ((tid & 63) == 0) { red[wid] = s; red[4 + wid] = s2; }
  __syncthreads();
  s  = red[0] + red[1] + red[2] + red[3];
  s2 = red[4] + red[5] + red[6] + red[7];
  const float mu  = s * (1.0f / 1024.0f);
  float var = s2 * (1.0f / 1024.0f) - mu * mu;
  var = fmaxf(var, 0.0f);
  const float rs = rsqrtf(var + 1e-5f);
  const float4 g = *(const float4*)&sc[tid * 4];
  const float4 o = *(const float4*)&off[tid * 4];
  bf16x4_v y;
  y[0] = (bf16_t)((v.x - mu) * rs * g.x + o.x);
  y[1] = (bf16_t)((v.y - mu) * rs * g.y + o.y);
  y[2] = (bf16_t)((v.z - mu) * rs * g.z + o.z);
  y[3] = (bf16_t)((v.w - mu) * rs * g.w + o.w);
  *(bf16x4_v*)&Y[(size_t)row * 1024 + tid * 4] = y;
}

// ------------------------------------------------------- transpose f32->bf16
__global__ __launch_bounds__(256) void transpose_kernel(
    const float* __restrict__ Win, bf16_t* __restrict__ Wt, int R, int C)
{
  __shared__ float t[32][33];
  const int tx = threadIdx.x & 31;
  const int ty = (threadIdx.x >> 5) << 2;
  const int r0 = blockIdx.y * 32;
  const int c0 = blockIdx.x * 32;
#pragma unroll
  for (int r = 0; r < 4; ++r)
    t[ty + r][tx] = Win[(size_t)(r0 + ty + r) * C + (c0 + tx)];
  __syncthreads();
#pragma unroll
  for (int r = 0; r < 4; ++r)
    Wt[(size_t)(c0 + ty + r) * R + (r0 + tx)] = (bf16_t)t[tx][ty + r];
}

// ------------------------------------------------- 256x256x64 8-wave GEMM
// MODE 1: H[(row*4+kgrp)*4096+m] = gelu(Y*W1t(rolled) + b1)   (bf16 out)
// MODE 2: OUT[row*1024+w] = X[row*1024+w] + H*W2t + b2        (f32 out)
// Both operands B^T layout, K stride 4096. LDS col-swizzle: byte ^= ((row&7)<<4),
// applied on gll global source (LDS stays linear) and on ds_read address.
// NOTE: kk's 64-byte step must be INSIDE the XOR (cs0/cs1), never added after
// (bit-6 carry walks into the next row for lanes with (lane&7)>=4).

#define LOADA(DST, I0)                                                        \
  _Pragma("unroll") for (int di_ = 0; di_ < 2; ++di_) {                       \
    DST[di_][0] = *(const bf16x8_v*)(Ab + arow + ((I0) + di_) * 2048 + cs0);  \
    DST[di_][1] = *(const bf16x8_v*)(Ab + arow + ((I0) + di_) * 2048 + cs1);  \
  }

#define MFMA2(AV, I0)                                                         \
  __builtin_amdgcn_s_setprio(1);                                              \
  _Pragma("unroll") for (int di_ = 0; di_ < 2; ++di_)                         \
  _Pragma("unroll") for (int kk_ = 0; kk_ < 2; ++kk_)                         \
  _Pragma("unroll") for (int j_ = 0; j_ < 4; ++j_)                            \
    acc[(I0) + di_][j_] = __builtin_amdgcn_mfma_f32_16x16x32_bf16(            \
        AV[di_][kk_], bfrag[j_][kk_], acc[(I0) + di_][j_], 0, 0, 0);          \
  __builtin_amdgcn_s_setprio(0);

#define ISSUE_A(NB, F, Q)                                                     \
  gll16(Asrc + ((size_t)(Q) * 64 * 4096) + (size_t)(F) * 64,                  \
        (char*)(&As[NB][0]) + (Q) * 8192 + ldsdst)
#define ISSUE_B(NB, F, Q)                                                     \
  gll16(Bsrc + ((size_t)(Q) * 64 * 4096) +                                    \
            (MODE == 1 ? ((((F) * 64) + rolloff) & 4095) : ((F) * 64)),       \
        (char*)(&Bs[NB][0]) + (Q) * 8192 + ldsdst)

template<int MODE>
__global__ __launch_bounds__(512, 2) void gemm256_kernel(
    const bf16_t* __restrict__ Ag, const bf16_t* __restrict__ Bg,
    const float* __restrict__ bias, const float* __restrict__ Xres,
    void* __restrict__ Out, long rowbase)
{
  __shared__ __align__(16) bf16_t As[2][256 * 64];
  __shared__ __align__(16) bf16_t Bs[2][256 * 64];

  const int tid  = threadIdx.x;
  const int lane = tid & 63;
  const int wid  = tid >> 6;
  const int wm   = wid >> 2;   // 0..1
  const int wn   = wid & 3;    // 0..3

  // XCD-bijective block swizzle (nwg % 8 == 0 by construction)
  const int nwgx = gridDim.x;
  const int nwg  = nwgx * gridDim.y;
  const int flat = blockIdx.y * nwgx + blockIdx.x;
  const int swz  = (flat & 7) * (nwg >> 3) + (flat >> 3);
  const int bm   = swz % nwgx;
  const int bnl  = swz / nwgx;

  int kgrp = 0, m0, rolloff = 0;
  if (MODE == 1) { kgrp = bnl >> 4; m0 = (bnl & 15) << 8; rolloff = ((4 - kgrp) & 3) << 10; }
  else           { m0 = bnl << 8; }

  // staging: thread covers LDS bytes q*8192 + tid*16 -> row=tid/8+q*64, colbyte=(tid&7)*16
  // source colbyte XOR'd with ((row&7)<<4) so LDS holds G[row][cb ^ s(row)]
  const int trow = tid >> 3;
  const int scb  = (((tid & 7) ^ (trow & 7)) << 4);
  const bf16_t* Asrc = Ag + (size_t)(bm * 256 + trow) * 4096 + (scb >> 1);
  const bf16_t* Bsrc = Bg + (size_t)(m0 + trow) * 4096 + (scb >> 1);
  const int ldsdst = (wid << 10);

  // fragment read offsets (bytes); row&7 == lane&7 for all fragment rows
  const int arow = (wm * 128 + (lane & 15)) * 128;
  const int brow = (wn * 64  + (lane & 15)) * 128;
  const int cs0  = (((lane >> 4) << 4)     ) ^ ((lane & 7) << 4);
  const int cs1  = (((lane >> 4) << 4) | 64) ^ ((lane & 7) << 4);

  f32x4_v  acc[8][4] = {};
  bf16x8_v bfrag[4][2];

  // prologue: stage tile 0
#pragma unroll
  for (int q = 0; q < 4; ++q) ISSUE_A(0, 0, q);
#pragma unroll
  for (int q = 0; q < 4; ++q) ISSUE_B(0, 0, q);
  WAIT_VM0();
  BARRIER();

  int cur = 0;
  for (int f = 0; f < 64; ++f) {
    const char* Ab = (const char*)(&As[cur][0]);
    const char* Bb = (const char*)(&Bs[cur][0]);
    const int  nb = cur ^ 1;
    const bool st = (f < 63);

    { // phase 0: all B frags + A i=0,1 ; stage 4 of 8
#pragma unroll
      for (int j = 0; j < 4; ++j) {
        bfrag[j][0] = *(const bf16x8_v*)(Bb + brow + j * 2048 + cs0);
        bfrag[j][1] = *(const bf16x8_v*)(Bb + brow + j * 2048 + cs1);
      }
      bf16x8_v av[2][2];
      LOADA(av, 0);
      if (st) { ISSUE_A(nb, f + 1, 0); ISSUE_A(nb, f + 1, 1);
                ISSUE_B(nb, f + 1, 0); ISSUE_B(nb, f + 1, 1); }
      BARRIER();
      MFMA2(av, 0);
      BARRIER();
    }
    { // phase 1: A i=2,3 ; stage remaining 4
      bf16x8_v av[2][2];
      LOADA(av, 2);
      if (st) { ISSUE_A(nb, f + 1, 2); ISSUE_A(nb, f + 1, 3);
                ISSUE_B(nb, f + 1, 2); ISSUE_B(nb, f + 1, 3); }
      BARRIER();
      MFMA2(av, 2);
      BARRIER();
    }
    { // phase 2: A i=4,5
      bf16x8_v av[2][2];
      LOADA(av, 4);
      BARRIER();
      MFMA2(av, 4);
      BARRIER();
    }
    { // phase 3: A i=6,7 ; publish next buffer
      bf16x8_v av[2][2];
      LOADA(av, 6);
      BARRIER();
      MFMA2(av, 6);
      if (st) WAIT_VM0();   // own 8 gll slices for tile f+1, issued >=2 phases ago
      BARRIER();
    }
    cur = nb;
  }

  const int cb16 = lane & 15;
  const int r4   = (lane >> 4) << 2;
  if (MODE == 1) {
    bf16_t* H = (bf16_t*)Out;
#pragma unroll
    for (int j = 0; j < 4; ++j) {
      const int m = m0 + wn * 64 + j * 16 + cb16;
      const float bv = bias[m];
#pragma unroll
      for (int i = 0; i < 8; ++i) {
        const int browi = bm * 256 + wm * 128 + i * 16 + r4;
#pragma unroll
        for (int r = 0; r < 4; ++r) {
          float v = acc[i][j][r] + bv;
          H[((size_t)(browi + r) * 4 + kgrp) * 4096 + m] = (bf16_t)gelu_tanh(v);
        }
      }
    }
  } else {
    float* O = (float*)Out;
#pragma unroll
    for (int j = 0; j < 4; ++j) {
      const int w = m0 + wn * 64 + j * 16 + cb16;
      const float bv = bias[w];
#pragma unroll
      for (int i = 0; i < 8; ++i) {
        const long row = rowbase + bm * 256 + wm * 128 + i * 16 + r4;
#pragma unroll
        for (int r = 0; r < 4; ++r)
          O[(size_t)(row + r) * 1024 + w] =
              Xres[(size_t)(row + r) * 1024 + w] + acc[i][j][r] + bv;
      }
    }
  }
}

// ----------------------------------------------------------------- launch
extern "C" void kernel_launch(void* const* d_in, const int* in_sizes, int n_in,
                              void* d_out, int out_size, void* d_ws, size_t ws_size,
                              hipStream_t stream)
{
  const float* x   = (const float*)d_in[0];
  const float* lns = (const float*)d_in[1];
  const float* lno = (const float*)d_in[2];
  const float* W1  = (const float*)d_in[3];
  const float* b1  = (const float*)d_in[4];
  const float* W2  = (const float*)d_in[5];
  const float* b2  = (const float*)d_in[6];
  float* out = (float*)d_out;

  char* ws = (char*)d_ws;
  const size_t W1OFF = (size_t)64 << 20;   // Y: 64 MB
  const size_t W2OFF = (size_t)96 << 20;   // W1t: 32 MB
  const size_t HOFF  = (size_t)104 << 20;  // W2t: 8 MB
  bf16_t* Y   = (bf16_t*)(ws);
  bf16_t* W1t = (bf16_t*)(ws + W1OFF);
  bf16_t* W2t = (bf16_t*)(ws + W2OFF);
  bf16_t* H   = (bf16_t*)(ws + HOFF);

  ln_kernel<<<32768, 256, 0, stream>>>(x, lns, lno, Y);
  transpose_kernel<<<dim3(128, 128), 256, 0, stream>>>(W1, W1t, 4096, 4096);
  transpose_kernel<<<dim3(32, 128), 256, 0, stream>>>(W2, W2t, 4096, 1024);

  const size_t per_row = (size_t)4 * 4096 * 2;
  long chunk = 8192;
  if (ws_size < HOFF + (size_t)8192 * per_row) {
    long maxb = (long)((ws_size - HOFF) / per_row);
    chunk = maxb & ~255L;
    if (chunk < 256) chunk = 256;
  }
  for (long b0 = 0; b0 < 8192; b0 += chunk) {
    const long cb = (8192 - b0 < chunk) ? (8192 - b0) : chunk;
    gemm256_kernel<1><<<dim3(cb / 256, 64), 512, 0, stream>>>(
        Y + (size_t)b0 * 4096, W1t, b1, nullptr, (void*)H, 0);
    gemm256_kernel<2><<<dim3((cb * 4) / 256, 4), 512, 0, stream>>>(
        H, W2t, b2, x, (void*)out, b0 * 4);
  }
}

// Round 4
// 1472.397 us; speedup vs baseline: 1.2402x; 1.0276x over previous
//
#include <hip/hip_runtime.h>
#include <hip/hip_bf16.h>
#include <cstdint>
#include <cstddef>

typedef __bf16 bf16_t;
typedef __bf16 bf16x4_v __attribute__((ext_vector_type(4)));
typedef __bf16 bf16x8_v __attribute__((ext_vector_type(8)));
typedef float  f32x4_v  __attribute__((ext_vector_type(4)));

// async global->LDS, 16B/lane; LDS dest = wave-uniform base + lane*16
__device__ __forceinline__ void gll16(const void* g, void* l) {
  __builtin_amdgcn_global_load_lds(
      (const __attribute__((address_space(1))) void*)g,
      (__attribute__((address_space(3))) void*)l, 16, 0, 0);
}

// raw barrier: does NOT drain vmcnt (unlike __syncthreads)
#define BARRIER()  asm volatile("s_barrier" ::: "memory")
#define WAIT_VM(N) asm volatile("s_waitcnt vmcnt(" #N ")" ::: "memory")

__device__ __forceinline__ float gelu_tanh(float x) {
  // 0.5x(1+tanh(z)) == x * sigmoid(2z); NaN-free at extremes
  float z = 0.79788456080286535588f * (x + 0.044715f * x * x * x);
  return x / (1.0f + __expf(-2.0f * z));
}

// ---------------------------------------------------------------- LayerNorm
__global__ __launch_bounds__(256) void ln_kernel(
    const float* __restrict__ X, const float* __restrict__ sc,
    const float* __restrict__ off, bf16_t* __restrict__ Y)
{
  const int row = blockIdx.x;
  const int tid = threadIdx.x;
  const float4 v = *(const float4*)&X[(size_t)row * 1024 + tid * 4];
  float s  = v.x + v.y + v.z + v.w;
  float s2 = v.x * v.x + v.y * v.y + v.z * v.z + v.w * v.w;
#pragma unroll
  for (int m = 1; m < 64; m <<= 1) {
    s  += __shfl_xor(s, m);
    s2 += __shfl_xor(s2, m);
  }
  __shared__ float red[8];
  const int wid = tid >> 6;
  if ((tid & 63) == 0) { red[wid] = s; red[4 + wid] = s2; }
  __syncthreads();
  s  = red[0] + red[1] + red[2] + red[3];
  s2 = red[4] + red[5] + red[6] + red[7];
  const float mu  = s * (1.0f / 1024.0f);
  float var = s2 * (1.0f / 1024.0f) - mu * mu;
  var = fmaxf(var, 0.0f);
  const float rs = rsqrtf(var + 1e-5f);
  const float4 g = *(const float4*)&sc[tid * 4];
  const float4 o = *(const float4*)&off[tid * 4];
  bf16x4_v y;
  y[0] = (bf16_t)((v.x - mu) * rs * g.x + o.x);
  y[1] = (bf16_t)((v.y - mu) * rs * g.y + o.y);
  y[2] = (bf16_t)((v.z - mu) * rs * g.z + o.z);
  y[3] = (bf16_t)((v.w - mu) * rs * g.w + o.w);
  *(bf16x4_v*)&Y[(size_t)row * 1024 + tid * 4] = y;
}

// ------------------------------------------------------- transpose f32->bf16
__global__ __launch_bounds__(256) void transpose_kernel(
    const float* __restrict__ Win, bf16_t* __restrict__ Wt, int R, int C)
{
  __shared__ float t[32][33];
  const int tx = threadIdx.x & 31;
  const int ty = (threadIdx.x >> 5) << 2;
  const int r0 = blockIdx.y * 32;
  const int c0 = blockIdx.x * 32;
#pragma unroll
  for (int r = 0; r < 4; ++r)
    t[ty + r][tx] = Win[(size_t)(r0 + ty + r) * C + (c0 + tx)];
  __syncthreads();
#pragma unroll
  for (int r = 0; r < 4; ++r)
    Wt[(size_t)(c0 + ty + r) * R + (r0 + tx)] = (bf16_t)t[tx][ty + r];
}

// ------------------------------------------------- 256x256x64 8-wave GEMM
// MODE 1: H[(row*4+kgrp)*4096+m] = gelu(Y*W1t(rolled) + b1)   (bf16 out)
// MODE 2: OUT[row*1024+w] = X[row*1024+w] + H*W2t + b2        (f32 out)
// Both operands B^T layout, K stride 4096. LDS col-swizzle byte ^= ((row&7)<<4)
// on gll global source (LDS linear) and on ds_read address; kk's 64B step is
// inside the XOR (cs0/cs1) to avoid bit-6 carry.
// T4 counted-vmcnt: per tile, stage issue order = B0..B3 (ph0), A0,A2,A1,A3
// (ph1). ph3-end waits vmcnt(2) (A1,A3 stay in flight; read only at next ph2);
// ph1-end waits vmcnt(8) (retires prior tile's A1,A3 under the 8 new issues).

#define LOADA(DST, I0)                                                        \
  _Pragma("unroll") for (int di_ = 0; di_ < 2; ++di_) {                       \
    DST[di_][0] = *(const bf16x8_v*)(Ab + arow + ((I0) + di_) * 2048 + cs0);  \
    DST[di_][1] = *(const bf16x8_v*)(Ab + arow + ((I0) + di_) * 2048 + cs1);  \
  }

#define MFMA2(AV, I0)                                                         \
  __builtin_amdgcn_s_setprio(1);                                              \
  _Pragma("unroll") for (int di_ = 0; di_ < 2; ++di_)                         \
  _Pragma("unroll") for (int kk_ = 0; kk_ < 2; ++kk_)                         \
  _Pragma("unroll") for (int j_ = 0; j_ < 4; ++j_)                            \
    acc[(I0) + di_][j_] = __builtin_amdgcn_mfma_f32_16x16x32_bf16(            \
        AV[di_][kk_], bfrag[j_][kk_], acc[(I0) + di_][j_], 0, 0, 0);          \
  __builtin_amdgcn_s_setprio(0);

#define ISSUE_A(NB, F, Q)                                                     \
  gll16(Asrc + ((size_t)(Q) * 64 * 4096) + (size_t)(F) * 64,                  \
        (char*)(&As[NB][0]) + (Q) * 8192 + ldsdst)
#define ISSUE_B(NB, F, Q)                                                     \
  gll16(Bsrc + ((size_t)(Q) * 64 * 4096) +                                    \
            (MODE == 1 ? ((((F) * 64) + rolloff) & 4095) : ((F) * 64)),       \
        (char*)(&Bs[NB][0]) + (Q) * 8192 + ldsdst)

template<int MODE>
__global__ __launch_bounds__(512, 2) void gemm256_kernel(
    const bf16_t* __restrict__ Ag, const bf16_t* __restrict__ Bg,
    const float* __restrict__ bias, const float* __restrict__ Xres,
    void* __restrict__ Out, long rowbase)
{
  __shared__ __align__(16) bf16_t As[2][256 * 64];
  __shared__ __align__(16) bf16_t Bs[2][256 * 64];

  const int tid  = threadIdx.x;
  const int lane = tid & 63;
  const int wid  = tid >> 6;
  const int wm   = wid >> 2;   // 0..1
  const int wn   = wid & 3;    // 0..3

  // XCD-bijective block swizzle (nwg % 8 == 0 by construction)
  const int nwgx = gridDim.x;
  const int nwg  = nwgx * gridDim.y;
  const int flat = blockIdx.y * nwgx + blockIdx.x;
  const int swz  = (flat & 7) * (nwg >> 3) + (flat >> 3);
  const int bm   = swz % nwgx;
  const int bnl  = swz / nwgx;

  int kgrp = 0, m0, rolloff = 0;
  if (MODE == 1) { kgrp = bnl >> 4; m0 = (bnl & 15) << 8; rolloff = ((4 - kgrp) & 3) << 10; }
  else           { m0 = bnl << 8; }

  // staging: thread covers LDS bytes q*8192 + tid*16 -> row=tid/8+q*64, colbyte=(tid&7)*16
  const int trow = tid >> 3;
  const int scb  = (((tid & 7) ^ (trow & 7)) << 4);
  const bf16_t* Asrc = Ag + (size_t)(bm * 256 + trow) * 4096 + (scb >> 1);
  const bf16_t* Bsrc = Bg + (size_t)(m0 + trow) * 4096 + (scb >> 1);
  const int ldsdst = (wid << 10);

  // fragment read offsets (bytes); row&7 == lane&7 for all fragment rows
  const int arow = (wm * 128 + (lane & 15)) * 128;
  const int brow = (wn * 64  + (lane & 15)) * 128;
  const int cs0  = (((lane >> 4) << 4)     ) ^ ((lane & 7) << 4);
  const int cs1  = (((lane >> 4) << 4) | 64) ^ ((lane & 7) << 4);

  f32x4_v  acc[8][4] = {};
  bf16x8_v bfrag[4][2];

  // prologue: stage tile 0
#pragma unroll
  for (int q = 0; q < 4; ++q) ISSUE_B(0, 0, q);
#pragma unroll
  for (int q = 0; q < 4; ++q) ISSUE_A(0, 0, q);
  WAIT_VM(0);
  BARRIER();

  int cur = 0;
  for (int f = 0; f < 64; ++f) {
    const char* Ab = (const char*)(&As[cur][0]);
    const char* Bb = (const char*)(&Bs[cur][0]);
    const int  nb = cur ^ 1;
    const bool st = (f < 63);

    { // phase 0: all B frags + A i=0,1 ; stage next B quarters
#pragma unroll
      for (int j = 0; j < 4; ++j) {
        bfrag[j][0] = *(const bf16x8_v*)(Bb + brow + j * 2048 + cs0);
        bfrag[j][1] = *(const bf16x8_v*)(Bb + brow + j * 2048 + cs1);
      }
      bf16x8_v av[2][2];
      LOADA(av, 0);
      if (st) { ISSUE_B(nb, f + 1, 0); ISSUE_B(nb, f + 1, 1);
                ISSUE_B(nb, f + 1, 2); ISSUE_B(nb, f + 1, 3); }
      BARRIER();
      MFMA2(av, 0);
      BARRIER();
    }
    { // phase 1: A i=2,3 ; stage next A (early quarters first, late last)
      bf16x8_v av[2][2];
      LOADA(av, 2);
      if (st) { ISSUE_A(nb, f + 1, 0); ISSUE_A(nb, f + 1, 2);
                ISSUE_A(nb, f + 1, 1); ISSUE_A(nb, f + 1, 3); }
      BARRIER();
      MFMA2(av, 2);
      // retire previous tile's deferred A1/A3 before ph2 reads them
      if (st) { WAIT_VM(8); } else { WAIT_VM(0); }
      BARRIER();
    }
    { // phase 2: A i=4,5
      bf16x8_v av[2][2];
      LOADA(av, 4);
      BARRIER();
      MFMA2(av, 4);
      BARRIER();
    }
    { // phase 3: A i=6,7 ; publish next buffer (counted, not drained)
      bf16x8_v av[2][2];
      LOADA(av, 6);
      BARRIER();
      MFMA2(av, 6);
      if (st) WAIT_VM(2);   // B0..B3, A0, A2 landed; A1, A3 stay in flight
      BARRIER();
    }
    cur = nb;
  }

  const int cb16 = lane & 15;
  const int r4   = (lane >> 4) << 2;
  if (MODE == 1) {
    bf16_t* H = (bf16_t*)Out;
#pragma unroll
    for (int j = 0; j < 4; ++j) {
      const int m = m0 + wn * 64 + j * 16 + cb16;
      const float bv = bias[m];
#pragma unroll
      for (int i = 0; i < 8; ++i) {
        const int browi = bm * 256 + wm * 128 + i * 16 + r4;
#pragma unroll
        for (int r = 0; r < 4; ++r) {
          float v = acc[i][j][r] + bv;
          H[((size_t)(browi + r) * 4 + kgrp) * 4096 + m] = (bf16_t)gelu_tanh(v);
        }
      }
    }
  } else {
    float* O = (float*)Out;
#pragma unroll
    for (int j = 0; j < 4; ++j) {
      const int w = m0 + wn * 64 + j * 16 + cb16;
      const float bv = bias[w];
#pragma unroll
      for (int i = 0; i < 8; ++i) {
        const long row = rowbase + bm * 256 + wm * 128 + i * 16 + r4;
#pragma unroll
        for (int r = 0; r < 4; ++r)
          O[(size_t)(row + r) * 1024 + w] =
              Xres[(size_t)(row + r) * 1024 + w] + acc[i][j][r] + bv;
      }
    }
  }
}

// ----------------------------------------------------------------- launch
extern "C" void kernel_launch(void* const* d_in, const int* in_sizes, int n_in,
                              void* d_out, int out_size, void* d_ws, size_t ws_size,
                              hipStream_t stream)
{
  const float* x   = (const float*)d_in[0];
  const float* lns = (const float*)d_in[1];
  const float* lno = (const float*)d_in[2];
  const float* W1  = (const float*)d_in[3];
  const float* b1  = (const float*)d_in[4];
  const float* W2  = (const float*)d_in[5];
  const float* b2  = (const float*)d_in[6];
  float* out = (float*)d_out;

  char* ws = (char*)d_ws;
  const size_t W1OFF = (size_t)64 << 20;   // Y: 64 MB
  const size_t W2OFF = (size_t)96 << 20;   // W1t: 32 MB
  const size_t HOFF  = (size_t)104 << 20;  // W2t: 8 MB
  bf16_t* Y   = (bf16_t*)(ws);
  bf16_t* W1t = (bf16_t*)(ws + W1OFF);
  bf16_t* W2t = (bf16_t*)(ws + W2OFF);
  bf16_t* H   = (bf16_t*)(ws + HOFF);

  ln_kernel<<<32768, 256, 0, stream>>>(x, lns, lno, Y);
  transpose_kernel<<<dim3(128, 128), 256, 0, stream>>>(W1, W1t, 4096, 4096);
  transpose_kernel<<<dim3(32, 128), 256, 0, stream>>>(W2, W2t, 4096, 1024);

  const size_t per_row = (size_t)4 * 4096 * 2;
  long chunk = 8192;
  if (ws_size < HOFF + (size_t)8192 * per_row) {
    long maxb = (long)((ws_size - HOFF) / per_row);
    chunk = maxb & ~255L;
    if (chunk < 256) chunk = 256;
  }
  for (long b0 = 0; b0 < 8192; b0 += chunk) {
    const long cb = (8192 - b0 < chunk) ? (8192 - b0) : chunk;
    gemm256_kernel<1><<<dim3(cb / 256, 64), 512, 0, stream>>>(
        Y + (size_t)b0 * 4096, W1t, b1, nullptr, (void*)H, 0);
    gemm256_kernel<2><<<dim3((cb * 4) / 256, 4), 512, 0, stream>>>(
        H, W2t, b2, x, (void*)out, b0 * 4);
  }
}